// Round 6
// baseline (312.932 us; speedup 1.0000x reference)
//
#include <hip/hip_runtime.h>

// Problem constants (match reference)
#define BV    8
#define CV    16
#define NXV   512
#define NYV   512
#define NV    16384
#define NRES  90
#define NHV   5
#define TPB   256

#define NPTS  (BV * NV)             // 131072 points
#define TSH   6                     // 64x64-pixel tiles
#define TDIM  (NXV >> TSH)          // 8 tiles per axis
#define NBUCKB (TDIM * TDIM)        // 64 buckets per batch
#define NBUCK  (BV * NBUCKB)        // 512 buckets total

#define CPG   2                     // channels per gather workgroup
#define NCG   (CV / CPG)            // 8 channel groups
#define RROWS 68                    // staged rows  [r0-2, r0+66)
#define RCOLS 72                    // staged cols  [c0-4, c0+68)
#define RSEG  (RCOLS / 4)           // 18 real float4 per row
#define SEGP  19                    // padded row stride in float4 (76 floats)
#define SLOTS_PER_CH (RROWS * SEGP) // 1292
#define SLOTS (CPG * SLOTS_PER_CH)  // 2584 float4 = 41344 B LDS
#define CHB   (SLOTS_PER_CH * 16)   // 20672 B per channel
#define ROWB  (SEGP * 16)           // 304 B per row

#if __has_builtin(__builtin_amdgcn_exp2f)
#define EXP2 __builtin_amdgcn_exp2f
#else
#define EXP2 exp2f
#endif

// ---------------- kernel Z: zero bucket counts ----------------
__global__ void zero_counts_kernel(int* __restrict__ counts) {
    counts[threadIdx.x] = 0;
}

__device__ __forceinline__ int bucket_key(float rpx, float rpy, int i) {
    const int tr = ((int)rpx) >> TSH;   // row-tile 0..7
    const int tc = ((int)rpy) >> TSH;   // col-tile 0..7
    return (i >> 14) * NBUCKB + tr * TDIM + tc;
}

// ---------------- kernel A: histogram ----------------
__global__ __launch_bounds__(TPB) void bucket_count_kernel(
    const float* __restrict__ coords, int* __restrict__ counts)
{
    const int i = blockIdx.x * TPB + threadIdx.x;   // i = b*NV + n
    const float2 cd = *(const float2*)(coords + (size_t)i * 2);
    const float rpx = rintf(cd.y * (float)(NXV - 1));
    const float rpy = rintf(cd.x * (float)(NYV - 1));
    atomicAdd(&counts[bucket_key(rpx, rpy, i)], 1);
}

// ---------------- kernel B: exclusive scan over 512 buckets ----------------
__global__ __launch_bounds__(NBUCK) void scan_kernel(
    const int* __restrict__ counts, int* __restrict__ starts,
    int* __restrict__ cursors)
{
    __shared__ int sm[NBUCK];
    const int tid = threadIdx.x;
    const int v = counts[tid];
    sm[tid] = v;
    __syncthreads();
    #pragma unroll
    for (int off = 1; off < NBUCK; off <<= 1) {
        int t = sm[tid];
        if (tid >= off) t += sm[tid - off];
        __syncthreads();
        sm[tid] = t;
        __syncthreads();
    }
    const int e = sm[tid] - v;      // exclusive
    starts[tid]  = e;
    cursors[tid] = e;
}

// ---------------- kernel C: scatter + weights (fused) ----------------
__global__ __launch_bounds__(TPB) void scatter_weights_kernel(
    const float* __restrict__ coords,
    const float* __restrict__ s_ptr,
    const float* __restrict__ offn,    // [NRES]
    const float* __restrict__ offi,    // [NHV]
    int* __restrict__ cursors,
    float4* __restrict__ w8a, float4* __restrict__ w8b,
    float4* __restrict__ wx4, int4* __restrict__ off4,
    float4* __restrict__ misc, int* __restrict__ posOf)
{
    const int i = blockIdx.x * TPB + threadIdx.x;   // i = b*NV + n

    const float2 cd = *(const float2*)(coords + (size_t)i * 2);
    const float px  = cd.y * (float)(NXV - 1);
    const float py  = cd.x * (float)(NYV - 1);
    const float rpx = rintf(px);          // round-half-even == jnp.round
    const float rpy = rintf(py);

    const int pos = atomicAdd(&cursors[bucket_key(rpx, rpy, i)], 1);
    posOf[i] = pos;                       // inverse permutation (coalesced)

    const float s = s_ptr[0];
    const float k = -0.72134752044448169f / (s * s);  // -0.5*log2(e)/s^2
    // (1/(s*sqrt(2pi)) cancels in the w2d normalization)

    float wx[NHV], wy[NHV];
    float sx = 0.f, sy = 0.f;
    #pragma unroll
    for (int h = 0; h < NHV; ++h) {
        float ax = 0.f, ay = 0.f;
        #pragma unroll 6
        for (int t = 0; t < NRES / NHV; ++t) {
            const float off = offn[h * (NRES / NHV) + t];
            const float vx = fminf(fmaxf(rpx - off, 0.f), (float)NXV);
            const float vy = fminf(fmaxf(rpy - off, 0.f), (float)NXV);
            const float dx = vx - px;
            const float dy = vy - py;
            ax += EXP2(k * dx * dx);
            ay += EXP2(k * dy * dy);
        }
        wx[h] = ax; wy[h] = ay;
        sx += ax;  sy += ay;
    }
    const float inv = 1.0f / (sx * sy);   // w2d.sum() == (sum wx)*(sum wy)

    int ix[NHV], iy[NHV];
    #pragma unroll
    for (int h = 0; h < NHV; ++h) {
        const float fo = offi[h];
        ix[h] = (int)fminf(fmaxf(rintf(rpx - fo), 0.f), (float)(NXV - 1));
        iy[h] = (int)fminf(fmaxf(rintf(rpy - fo), 0.f), (float)(NXV - 1));
    }

    // column base aligned to float4; all 5 clamped cols live in [a, a+8)
    const int a = min(iy[NHV - 1] & ~3, NYV - 8);

    // scatter wy*inv into 8 slots (clamp duplicates accumulate)
    float w8[8];
    #pragma unroll
    for (int kk = 0; kk < 8; ++kk) {
        float w = 0.f;
        #pragma unroll
        for (int j = 0; j < NHV; ++j)
            w += (iy[j] - a == kk) ? wy[j] * inv : 0.f;
        w8[kk] = w;
    }

    w8a[pos] = make_float4(w8[0], w8[1], w8[2], w8[3]);
    w8b[pos] = make_float4(w8[4], w8[5], w8[6], w8[7]);
    wx4[pos] = make_float4(wx[0], wx[1], wx[2], wx[3]);
    off4[pos] = make_int4((ix[0] * NYV + a) * 4, (ix[1] * NYV + a) * 4,
                          (ix[2] * NYV + a) * 4, (ix[3] * NYV + a) * 4);
    misc[pos] = make_float4(wx[4], __int_as_float((ix[4] * NYV + a) * 4),
                            0.f, 0.f);
}

// ---------------- kernel G: tile-centric LDS gather -> tmp (point order) ----
// One WG per (64x64 tile, 2-channel group). Stage 68x72 halo x 2 channels
// into LDS (padded row stride, coalesced), each point-channel item reads
// 5 rows x 2 float4 from LDS, writes tmp fully coalesced in sorted order.
__global__ __launch_bounds__(TPB) void tile_gather_kernel(
    const float* __restrict__ x,
    const int* __restrict__ starts, const int* __restrict__ ends,
    const float4* __restrict__ w8a, const float4* __restrict__ w8b,
    const float4* __restrict__ wx4, const int4* __restrict__ off4,
    const float4* __restrict__ misc,
    float* __restrict__ tmp)           // [NCG][NPTS][CPG]
{
    __shared__ float4 lds[SLOTS];          // 41344 B

    const int bid = blockIdx.x;            // b*64 + tr*8 + tc
    const int cg  = blockIdx.y;            // channel group (0..7)
    const int b   = bid >> 6;
    const int tr  = (bid >> 3) & (TDIM - 1);
    const int tc  = bid & (TDIM - 1);
    const int r0  = tr << TSH, c0 = tc << TSH;
    const int R0  = min(max(r0 - 2, 0), NXV - RROWS);
    const int W0  = min(max(c0 - 4, 0), NYV - RCOLS);

    const int tid = threadIdx.x;
    const char* bx = (const char*)x + ((size_t)(b * CV + cg * CPG) << 20);

    // ---- stage region into LDS (padded stride; skip pad slot) ----
    for (int sslot = tid; sslot < SLOTS; sslot += TPB) {
        const int ch  = sslot / SLOTS_PER_CH;
        const int rem = sslot - ch * SLOTS_PER_CH;
        const int row = rem / SEGP;
        const int seg = rem - row * SEGP;
        if (seg < RSEG)
            lds[sslot] = *(const float4*)(bx + ((size_t)ch << 20)
                          + ((size_t)(R0 + row) << 11) + (W0 << 2) + (seg << 4));
    }
    __syncthreads();

    // ---- process this bucket's points x CPG channels ----
    const int s0    = starts[bid];
    const int total = (ends[bid] - s0) << 1;   // cnt * CPG
    const char* ldsb = (const char*)lds;
    float* tout = tmp + (size_t)cg * (NPTS * CPG);

    for (int item = tid; item < total; item += TPB) {
        const int p   = s0 + (item >> 1);
        const int chl = item & (CPG - 1);

        const float4 wa = w8a[p];
        const float4 wb = w8b[p];
        const float4 wr = wx4[p];
        const int4   o4 = off4[p];
        const float4 ms = misc[p];
        const float  we = ms.x;
        const int    oe = __float_as_int(ms.y);

        // absolute plane byte-offset -> LDS byte-offset
        const int basech = chl * CHB - R0 * ROWB - (W0 << 2);

        float acc = 0.f;
#define ROW(OFF, WROW) {                                                     \
        const int lo = basech + ((OFF) >> 11) * ROWB + ((OFF) & 2047);       \
        const float4 va = *(const float4*)(ldsb + lo);                       \
        const float4 vb = *(const float4*)(ldsb + lo + 16);                  \
        const float rs = va.x * wa.x + va.y * wa.y + va.z * wa.z +           \
                         va.w * wa.w + vb.x * wb.x + vb.y * wb.y +           \
                         vb.z * wb.z + vb.w * wb.w;                          \
        acc = fmaf(WROW, rs, acc); }

        ROW(o4.x, wr.x)
        ROW(o4.y, wr.y)
        ROW(o4.z, wr.z)
        ROW(o4.w, wr.w)
        ROW(oe,   we)
#undef ROW

        tout[(size_t)p * CPG + chl] = acc;   // fully coalesced
    }
}

// ---------------- kernel T: transpose tmp -> out (coalesced writes) --------
__global__ __launch_bounds__(TPB) void transpose_kernel(
    const float* __restrict__ tmp, const int* __restrict__ posOf,
    float* __restrict__ out)
{
    const int idx = blockIdx.x * TPB + threadIdx.x;   // (b*16+c)*16384 + n
    const int n = idx & (NV - 1);
    const int c = (idx >> 14) & (CV - 1);
    const int b = idx >> 18;
    const int p = posOf[(b << 14) | n];               // coalesced read
    out[idx] = tmp[(size_t)(c >> 1) * (NPTS * CPG) + (size_t)p * CPG + (c & 1)];
}

extern "C" void kernel_launch(void* const* d_in, const int* in_sizes, int n_in,
                              void* d_out, int out_size, void* d_ws, size_t ws_size,
                              hipStream_t stream) {
    const float* x      = (const float*)d_in[0];
    const float* coords = (const float*)d_in[1];
    const float* s_ptr  = (const float*)d_in[2];
    const float* offn   = (const float*)d_in[3];
    const float* offi   = (const float*)d_in[4];
    float* out = (float*)d_out;

    // workspace layout (16B-aligned arrays first); ~19 MB
    char* w = (char*)d_ws;
    float4* w8a  = (float4*)w;  w += (size_t)NPTS * 16;
    float4* w8b  = (float4*)w;  w += (size_t)NPTS * 16;
    float4* wx4  = (float4*)w;  w += (size_t)NPTS * 16;
    int4*   off4 = (int4*)w;    w += (size_t)NPTS * 16;
    float4* misc = (float4*)w;  w += (size_t)NPTS * 16;
    float*  tmp  = (float*)w;   w += (size_t)NPTS * CV * 4;   // 8 MiB
    int*    posOf = (int*)w;    w += (size_t)NPTS * 4;
    int*    counts  = (int*)w;  w += (size_t)NBUCK * 4;
    int*    starts  = (int*)w;  w += (size_t)NBUCK * 4;
    int*    cursors = (int*)w;

    zero_counts_kernel<<<dim3(1), dim3(NBUCK), 0, stream>>>(counts);
    bucket_count_kernel<<<dim3(NPTS / TPB), dim3(TPB), 0, stream>>>(coords, counts);
    scan_kernel<<<dim3(1), dim3(NBUCK), 0, stream>>>(counts, starts, cursors);
    scatter_weights_kernel<<<dim3(NPTS / TPB), dim3(TPB), 0, stream>>>(
        coords, s_ptr, offn, offi, cursors, w8a, w8b, wx4, off4, misc, posOf);

    dim3 grid(NBUCK, NCG, 1);
    tile_gather_kernel<<<grid, dim3(TPB), 0, stream>>>(
        x, starts, cursors, w8a, w8b, wx4, off4, misc, tmp);

    transpose_kernel<<<dim3(NPTS * CV / TPB), dim3(TPB), 0, stream>>>(
        tmp, posOf, out);
}

// Round 7
// 300.931 us; speedup vs baseline: 1.0399x; 1.0399x over previous
//
#include <hip/hip_runtime.h>

// Problem constants (match reference)
#define BV    8
#define CV    16
#define NXV   512
#define NYV   512
#define NV    16384
#define NRES  90
#define NHV   5
#define TPB   256

#define NPTS  (BV * NV)             // 131072 points
#define TSH   6                     // 64x64-pixel tiles
#define TDIM  (NXV >> TSH)          // 8 tiles per axis
#define NBUCKB (TDIM * TDIM)        // 64 buckets per batch
#define NBUCK  (BV * NBUCKB)        // 512 buckets total

#define RROWS 68                    // staged rows  [r0-2, r0+66)
#define RSEG  18                    // 72 cols = 18 float4 per row (no pad)
#define ROWB  (RSEG * 16)           // 288 B per row
#define SLOTS (RROWS * RSEG)        // 1224 float4 = 19584 B LDS -> 8 WGs/CU

#if __has_builtin(__builtin_amdgcn_exp2f)
#define EXP2 __builtin_amdgcn_exp2f
#else
#define EXP2 exp2f
#endif

// ---------------- kernel Z: zero bucket counts ----------------
__global__ void zero_counts_kernel(int* __restrict__ counts) {
    counts[threadIdx.x] = 0;
}

__device__ __forceinline__ int bucket_key(float rpx, float rpy, int i) {
    const int tr = ((int)rpx) >> TSH;   // row-tile 0..7
    const int tc = ((int)rpy) >> TSH;   // col-tile 0..7
    return (i >> 14) * NBUCKB + tr * TDIM + tc;
}

// ---------------- kernel A: histogram ----------------
__global__ __launch_bounds__(TPB) void bucket_count_kernel(
    const float* __restrict__ coords, int* __restrict__ counts)
{
    const int i = blockIdx.x * TPB + threadIdx.x;   // i = b*NV + n
    const float2 cd = *(const float2*)(coords + (size_t)i * 2);
    const float rpx = rintf(cd.y * (float)(NXV - 1));
    const float rpy = rintf(cd.x * (float)(NYV - 1));
    atomicAdd(&counts[bucket_key(rpx, rpy, i)], 1);
}

// ---------------- kernel B: exclusive scan over 512 buckets ----------------
__global__ __launch_bounds__(NBUCK) void scan_kernel(
    const int* __restrict__ counts, int* __restrict__ starts,
    int* __restrict__ cursors)
{
    __shared__ int sm[NBUCK];
    const int tid = threadIdx.x;
    const int v = counts[tid];
    sm[tid] = v;
    __syncthreads();
    #pragma unroll
    for (int off = 1; off < NBUCK; off <<= 1) {
        int t = sm[tid];
        if (tid >= off) t += sm[tid - off];
        __syncthreads();
        sm[tid] = t;
        __syncthreads();
    }
    const int e = sm[tid] - v;      // exclusive
    starts[tid]  = e;
    cursors[tid] = e;
}

// ---------------- kernel C: scatter + weights (fused) ----------------
__global__ __launch_bounds__(TPB) void scatter_weights_kernel(
    const float* __restrict__ coords,
    const float* __restrict__ s_ptr,
    const float* __restrict__ offn,    // [NRES]
    const float* __restrict__ offi,    // [NHV]
    int* __restrict__ cursors,
    float4* __restrict__ w8a, float4* __restrict__ w8b,
    float4* __restrict__ wx4, int4* __restrict__ off4,
    float4* __restrict__ misc)
{
    const int i = blockIdx.x * TPB + threadIdx.x;   // i = b*NV + n

    const float2 cd = *(const float2*)(coords + (size_t)i * 2);
    const float px  = cd.y * (float)(NXV - 1);
    const float py  = cd.x * (float)(NYV - 1);
    const float rpx = rintf(px);          // round-half-even == jnp.round
    const float rpy = rintf(py);

    const int pos = atomicAdd(&cursors[bucket_key(rpx, rpy, i)], 1);

    const float s = s_ptr[0];
    const float k = -0.72134752044448169f / (s * s);  // -0.5*log2(e)/s^2
    // (1/(s*sqrt(2pi)) cancels in the w2d normalization)

    float wx[NHV], wy[NHV];
    float sx = 0.f, sy = 0.f;
    #pragma unroll
    for (int h = 0; h < NHV; ++h) {
        float ax = 0.f, ay = 0.f;
        #pragma unroll 6
        for (int t = 0; t < NRES / NHV; ++t) {
            const float off = offn[h * (NRES / NHV) + t];
            const float vx = fminf(fmaxf(rpx - off, 0.f), (float)NXV);
            const float vy = fminf(fmaxf(rpy - off, 0.f), (float)NXV);
            const float dx = vx - px;
            const float dy = vy - py;
            ax += EXP2(k * dx * dx);
            ay += EXP2(k * dy * dy);
        }
        wx[h] = ax; wy[h] = ay;
        sx += ax;  sy += ay;
    }
    const float inv = 1.0f / (sx * sy);   // w2d.sum() == (sum wx)*(sum wy)

    int ix[NHV], iy[NHV];
    #pragma unroll
    for (int h = 0; h < NHV; ++h) {
        const float fo = offi[h];
        ix[h] = (int)fminf(fmaxf(rintf(rpx - fo), 0.f), (float)(NXV - 1));
        iy[h] = (int)fminf(fmaxf(rintf(rpy - fo), 0.f), (float)(NXV - 1));
    }

    // column base aligned to float4; all 5 clamped cols live in [a, a+8)
    const int a = min(iy[NHV - 1] & ~3, NYV - 8);

    // scatter wy*inv into 8 slots (clamp duplicates accumulate)
    float w8[8];
    #pragma unroll
    for (int kk = 0; kk < 8; ++kk) {
        float w = 0.f;
        #pragma unroll
        for (int j = 0; j < NHV; ++j)
            w += (iy[j] - a == kk) ? wy[j] * inv : 0.f;
        w8[kk] = w;
    }

    w8a[pos] = make_float4(w8[0], w8[1], w8[2], w8[3]);
    w8b[pos] = make_float4(w8[4], w8[5], w8[6], w8[7]);
    wx4[pos] = make_float4(wx[0], wx[1], wx[2], wx[3]);
    off4[pos] = make_int4((ix[0] * NYV + a) * 4, (ix[1] * NYV + a) * 4,
                          (ix[2] * NYV + a) * 4, (ix[3] * NYV + a) * 4);
    misc[pos] = make_float4(wx[4], __int_as_float((ix[4] * NYV + a) * 4),
                            __int_as_float(i), 0.f);
}

// ---------------- kernel G: tile-centric LDS gather, 1 channel/WG ----------
// One WG per (64x64 tile, channel). Stage 68x72 halo (19.6 KB -> 8 WGs/CU,
// 32 waves/CU), each point reads 5 rows x 2 float4 from LDS, writes out
// directly (scattered 4B stores - fire-and-forget, proven cheap in R5).
__global__ __launch_bounds__(TPB, 8) void tile_gather_kernel(
    const float* __restrict__ x,
    const int* __restrict__ starts, const int* __restrict__ ends,
    const float4* __restrict__ w8a, const float4* __restrict__ w8b,
    const float4* __restrict__ wx4, const int4* __restrict__ off4,
    const float4* __restrict__ misc,
    float* __restrict__ out)
{
    __shared__ float4 lds[SLOTS];          // 19584 B

    const int bid = blockIdx.x;            // b*64 + tr*8 + tc
    const int c   = blockIdx.y;            // channel (0..15)
    const int b   = bid >> 6;
    const int tr  = (bid >> 3) & (TDIM - 1);
    const int tc  = bid & (TDIM - 1);
    const int r0  = tr << TSH, c0 = tc << TSH;
    const int R0  = min(max(r0 - 2, 0), NXV - RROWS);
    const int W0  = min(max(c0 - 4, 0), NYV - RSEG * 4);

    const int tid = threadIdx.x;
    const char* bx = (const char*)x + ((size_t)(b * CV + c) << 20);

    // ---- stage 68x72 region into LDS (dense, coalesced) ----
    #pragma unroll
    for (int kk = 0; kk < (SLOTS + TPB - 1) / TPB; ++kk) {
        const int slot = tid + kk * TPB;
        if (slot < SLOTS) {
            const int row = slot / RSEG;
            const int seg = slot - row * RSEG;
            lds[slot] = *(const float4*)(bx + ((size_t)(R0 + row) << 11)
                                            + (W0 << 2) + (seg << 4));
        }
    }
    __syncthreads();

    // ---- process this bucket's points (1 item per point) ----
    const int s0 = starts[bid];
    const int e1 = ends[bid];
    const char* ldsb = (const char*)lds;
    const int base0 = -R0 * ROWB - (W0 << 2);

    for (int p = s0 + tid; p < e1; p += TPB) {
        const float4 wa = w8a[p];
        const float4 wb = w8b[p];
        const float4 wr = wx4[p];
        const int4   o4 = off4[p];
        const float4 ms = misc[p];
        const float  we = ms.x;
        const int    oe = __float_as_int(ms.y);
        const int    i  = __float_as_int(ms.z);
        const int    n  = i & (NV - 1);

        float acc = 0.f;
#define ROW(OFF, WROW) {                                                     \
        const int lo = base0 + ((OFF) >> 11) * ROWB + ((OFF) & 2047);        \
        const float4 va = *(const float4*)(ldsb + lo);                       \
        const float4 vb = *(const float4*)(ldsb + lo + 16);                  \
        const float rs = va.x * wa.x + va.y * wa.y + va.z * wa.z +           \
                         va.w * wa.w + vb.x * wb.x + vb.y * wb.y +           \
                         vb.z * wb.z + vb.w * wb.w;                          \
        acc = fmaf(WROW, rs, acc); }

        ROW(o4.x, wr.x)
        ROW(o4.y, wr.y)
        ROW(o4.z, wr.z)
        ROW(o4.w, wr.w)
        ROW(oe,   we)
#undef ROW

        out[(((size_t)(b * CV + c)) << 14) + n] = acc;   // scattered 4B store
    }
}

extern "C" void kernel_launch(void* const* d_in, const int* in_sizes, int n_in,
                              void* d_out, int out_size, void* d_ws, size_t ws_size,
                              hipStream_t stream) {
    const float* x      = (const float*)d_in[0];
    const float* coords = (const float*)d_in[1];
    const float* s_ptr  = (const float*)d_in[2];
    const float* offn   = (const float*)d_in[3];
    const float* offi   = (const float*)d_in[4];
    float* out = (float*)d_out;

    // workspace layout (16B-aligned arrays first); ~10.5 MB
    char* w = (char*)d_ws;
    float4* w8a  = (float4*)w;  w += (size_t)NPTS * 16;
    float4* w8b  = (float4*)w;  w += (size_t)NPTS * 16;
    float4* wx4  = (float4*)w;  w += (size_t)NPTS * 16;
    int4*   off4 = (int4*)w;    w += (size_t)NPTS * 16;
    float4* misc = (float4*)w;  w += (size_t)NPTS * 16;
    int*    counts  = (int*)w;  w += (size_t)NBUCK * 4;
    int*    starts  = (int*)w;  w += (size_t)NBUCK * 4;
    int*    cursors = (int*)w;

    zero_counts_kernel<<<dim3(1), dim3(NBUCK), 0, stream>>>(counts);
    bucket_count_kernel<<<dim3(NPTS / TPB), dim3(TPB), 0, stream>>>(coords, counts);
    scan_kernel<<<dim3(1), dim3(NBUCK), 0, stream>>>(counts, starts, cursors);
    scatter_weights_kernel<<<dim3(NPTS / TPB), dim3(TPB), 0, stream>>>(
        coords, s_ptr, offn, offi, cursors, w8a, w8b, wx4, off4, misc);

    dim3 grid(NBUCK, CV, 1);
    tile_gather_kernel<<<grid, dim3(TPB), 0, stream>>>(
        x, starts, cursors, w8a, w8b, wx4, off4, misc, out);
}